// Round 1
// baseline (334.664 us; speedup 1.0000x reference)
//
#include <hip/hip_runtime.h>

#define T_STEPS 345
#define B_SZ    128
#define IN_SZ   13
#define H_SZ    128
#define OUT_SZ  9

// One block = one wave (64 lanes) = one batch element's full T=345 scan.
// Lane owns hidden neurons h=lane and h=lane+64 (state + weights in regs).
// Layer-2 reduction: 6-level shfl_xor butterfly over the 9 output partials.
__global__ __launch_bounds__(64, 1)
void snn_scan_kernel(const float* __restrict__ x,
                     const float* __restrict__ W1,
                     const float* __restrict__ b1,
                     const float* __restrict__ W2,
                     const float* __restrict__ b2,
                     const float* __restrict__ beta1p,
                     const float* __restrict__ thr1p,
                     const float* __restrict__ beta2p,
                     const float* __restrict__ thr2p,
                     float* __restrict__ out)
{
    const int b    = blockIdx.x;
    const int lane = threadIdx.x;   // 0..63

    __shared__ float xs[IN_SZ * T_STEPS];   // 17,940 B — x[b,:,:] staged once

    const float* xb = x + (size_t)b * (IN_SZ * T_STEPS);
    for (int i = lane; i < IN_SZ * T_STEPS; i += 64)
        xs[i] = xb[i];

    const float bt1 = fminf(fmaxf(beta1p[0], 0.0f), 1.0f);
    const float th1 = thr1p[0];
    const float bt2 = fminf(fmaxf(beta2p[0], 0.0f), 1.0f);
    const float th2 = thr2p[0];

    // Per-lane weights for the two owned hidden neurons
    const int ha = lane;
    const int hb = lane + 64;
    float w1a[IN_SZ], w1b[IN_SZ];
#pragma unroll
    for (int c = 0; c < IN_SZ; ++c) {
        w1a[c] = W1[ha * IN_SZ + c];
        w1b[c] = W1[hb * IN_SZ + c];
    }
    const float b1a = b1[ha];
    const float b1b = b1[hb];

    float w2a[OUT_SZ], w2b[OUT_SZ];
#pragma unroll
    for (int o = 0; o < OUT_SZ; ++o) {
        w2a[o] = W2[o * H_SZ + ha];
        w2b[o] = W2[o * H_SZ + hb];
    }

    // Lane o (< 9) owns output neuron o
    const float b2o = (lane < OUT_SZ) ? b2[lane] : 0.0f;

    float mem1a = 0.0f, mem1b = 0.0f;
    float mem2  = 0.0f;   // meaningful for lanes 0..8 only

    float* __restrict__ out_spk = out;
    float* __restrict__ out_mem = out + (size_t)T_STEPS * B_SZ * OUT_SZ;

    __syncthreads();

    for (int t = 0; t < T_STEPS; ++t) {
        // ---- layer 1: cur1 = W1 @ x[:,t] + b1 (per owned neuron) ----
        float ca = b1a, cb = b1b;
#pragma unroll
        for (int c = 0; c < IN_SZ; ++c) {
            const float xv = xs[c * T_STEPS + t];   // wave-uniform LDS broadcast
            ca = fmaf(xv, w1a[c], ca);
            cb = fmaf(xv, w1b[c], cb);
        }
        mem1a = fmaf(bt1, mem1a, ca);
        mem1b = fmaf(bt1, mem1b, cb);
        const float sa = (mem1a > th1) ? 1.0f : 0.0f;
        const float sb = (mem1b > th1) ? 1.0f : 0.0f;
        mem1a = fmaf(-sa, th1, mem1a);   // subtract-reset
        mem1b = fmaf(-sb, th1, mem1b);

        // ---- layer 2 partials: p[o] = sa*W2[o][ha] + sb*W2[o][hb] ----
        float p[OUT_SZ];
#pragma unroll
        for (int o = 0; o < OUT_SZ; ++o)
            p[o] = fmaf(sb, w2b[o], sa * w2a[o]);

        // ---- 64-lane butterfly reduction (9 independent values) ----
#pragma unroll
        for (int off = 32; off > 0; off >>= 1) {
#pragma unroll
            for (int o = 0; o < OUT_SZ; ++o)
                p[o] += __shfl_xor(p[o], off, 64);
        }

        // ---- lane o selects its output sum, updates mem2, stores ----
        float cur2 = p[0];
#pragma unroll
        for (int o = 1; o < OUT_SZ; ++o)
            cur2 = (lane == o) ? p[o] : cur2;
        cur2 += b2o;

        mem2 = fmaf(bt2, mem2, cur2);
        const float s2 = (mem2 > th2) ? 1.0f : 0.0f;
        mem2 = fmaf(-s2, th2, mem2);

        if (lane < OUT_SZ) {
            const size_t idx = (size_t)t * (B_SZ * OUT_SZ) + (size_t)b * OUT_SZ + lane;
            out_spk[idx] = s2;
            out_mem[idx] = mem2;
        }
    }
}

extern "C" void kernel_launch(void* const* d_in, const int* in_sizes, int n_in,
                              void* d_out, int out_size, void* d_ws, size_t ws_size,
                              hipStream_t stream) {
    const float* x     = (const float*)d_in[0];
    const float* W1    = (const float*)d_in[1];
    const float* b1    = (const float*)d_in[2];
    const float* W2    = (const float*)d_in[3];
    const float* b2    = (const float*)d_in[4];
    const float* beta1 = (const float*)d_in[5];
    const float* thr1  = (const float*)d_in[6];
    const float* beta2 = (const float*)d_in[7];
    const float* thr2  = (const float*)d_in[8];
    float* out = (float*)d_out;

    snn_scan_kernel<<<dim3(B_SZ), dim3(64), 0, stream>>>(
        x, W1, b1, W2, b2, beta1, thr1, beta2, thr2, out);
}

// Round 4
// 173.902 us; speedup vs baseline: 1.9244x; 1.9244x over previous
//
#include <hip/hip_runtime.h>

#define T_STEPS 345
#define B_SZ    128
#define IN_SZ   13
#define H_SZ    128
#define OUT_SZ  9
#define XPITCH  16   // padded floats per timestep row in LDS (64B-aligned rows)

// DPP-based add of shifted value; ctrl is a template param (builtin requires
// a frontend-constant). bound_ctrl=false: invalid source lanes read old_val=0.
template <int CTRL>
__device__ __forceinline__ float dpp_add(float x) {
    int y = __builtin_amdgcn_update_dpp(0, __float_as_int(x), CTRL, 0xf, 0xf, false);
    return x + __int_as_float(y);
}

// Full 64-lane sum on the VALU pipe; total lands in lane 63.
__device__ __forceinline__ float wave_sum64(float x) {
    x = dpp_add<0x111>(x); // row_shr:1
    x = dpp_add<0x112>(x); // row_shr:2
    x = dpp_add<0x114>(x); // row_shr:4
    x = dpp_add<0x118>(x); // row_shr:8  -> lane15 of each row-of-16 = row sum
    x = dpp_add<0x142>(x); // row_bcast:15 -> lane63 = rows 2+3, lane31 = rows 0+1
    x = dpp_add<0x143>(x); // row_bcast:31 -> lane63 = all 64
    return x;
}

// One block = one wave = one batch element's full T=345 scan.
// Layer-1 uses R1's exact single-chain FMA order (numerics that passed —
// a two-accumulator split flipped a marginal hidden spike in R3).
// Layer-2 reduction on the VALU pipe via DPP instead of ds_swizzle.
__global__ __launch_bounds__(64, 1)
void snn_scan_kernel(const float* __restrict__ x,
                     const float* __restrict__ W1,
                     const float* __restrict__ b1,
                     const float* __restrict__ W2,
                     const float* __restrict__ b2,
                     const float* __restrict__ beta1p,
                     const float* __restrict__ thr1p,
                     const float* __restrict__ beta2p,
                     const float* __restrict__ thr2p,
                     float* __restrict__ out)
{
    const int b    = blockIdx.x;
    const int lane = threadIdx.x;   // 0..63

    __shared__ float xst[T_STEPS * XPITCH];   // 22,080 B

    // Stage + transpose x[b,:,:] (13 x 345, c-major) -> xst[t*16 + c]
    const float* xb = x + (size_t)b * (IN_SZ * T_STEPS);
    for (int i = lane; i < IN_SZ * T_STEPS; i += 64) {
        const int c = i / T_STEPS;
        const int t = i - c * T_STEPS;
        xst[t * XPITCH + c] = xb[i];
    }

    const float bt1 = fminf(fmaxf(beta1p[0], 0.0f), 1.0f);
    const float th1 = thr1p[0];
    const float bt2 = fminf(fmaxf(beta2p[0], 0.0f), 1.0f);
    const float th2 = thr2p[0];

    // Per-lane weights for the two owned hidden neurons
    const int ha = lane;
    const int hb = lane + 64;
    float w1a[IN_SZ], w1b[IN_SZ];
#pragma unroll
    for (int c = 0; c < IN_SZ; ++c) {
        w1a[c] = W1[ha * IN_SZ + c];
        w1b[c] = W1[hb * IN_SZ + c];
    }
    const float b1a = b1[ha];
    const float b1b = b1[hb];

    float w2a[OUT_SZ], w2b[OUT_SZ];
#pragma unroll
    for (int o = 0; o < OUT_SZ; ++o) {
        w2a[o] = W2[o * H_SZ + ha];
        w2b[o] = W2[o * H_SZ + hb];
    }

    const float b2o = (lane < OUT_SZ) ? b2[lane] : 0.0f;

    float mem1a = 0.0f, mem1b = 0.0f;
    float mem2  = 0.0f;   // meaningful for lanes 0..8 only

    float* __restrict__ out_spk = out;
    float* __restrict__ out_mem = out + (size_t)T_STEPS * B_SZ * OUT_SZ;

    __syncthreads();

    // Prefetch t=0 (wave-uniform LDS reads)
    const float4* xq = (const float4*)xst;
    float4 q0 = xq[0], q1 = xq[1], q2 = xq[2];
    float  q3 = xst[12];

    for (int t = 0; t < T_STEPS; ++t) {
        const float xv[IN_SZ] = { q0.x, q0.y, q0.z, q0.w,
                                  q1.x, q1.y, q1.z, q1.w,
                                  q2.x, q2.y, q2.z, q2.w, q3 };

        // Prefetch next step (branchless; clamped index re-reads last row)
        const int tn = (t + 1 < T_STEPS) ? t + 1 : t;
        q0 = xq[tn * 4 + 0];
        q1 = xq[tn * 4 + 1];
        q2 = xq[tn * 4 + 2];
        q3 = xst[tn * XPITCH + 12];

        // ---- layer 1: R1's exact single-chain order (do not reorder!) ----
        float ca = b1a, cb = b1b;
#pragma unroll
        for (int c = 0; c < IN_SZ; ++c) {
            ca = fmaf(xv[c], w1a[c], ca);
            cb = fmaf(xv[c], w1b[c], cb);
        }

        mem1a = fmaf(bt1, mem1a, ca);
        mem1b = fmaf(bt1, mem1b, cb);
        const float sa = (mem1a > th1) ? 1.0f : 0.0f;
        const float sb = (mem1b > th1) ? 1.0f : 0.0f;
        mem1a = fmaf(-sa, th1, mem1a);   // subtract-reset
        mem1b = fmaf(-sb, th1, mem1b);

        // ---- layer 2 partials + DPP all-lane reduce (9 independent chains) ----
        float p[OUT_SZ];
#pragma unroll
        for (int o = 0; o < OUT_SZ; ++o)
            p[o] = fmaf(sb, w2b[o], sa * w2a[o]);
#pragma unroll
        for (int o = 0; o < OUT_SZ; ++o)
            p[o] = wave_sum64(p[o]);

        // ---- lane o grabs sum o from lane 63, updates mem2, stores ----
        float cur2 = b2o;
#pragma unroll
        for (int o = 0; o < OUT_SZ; ++o) {
            const float so = __int_as_float(
                __builtin_amdgcn_readlane(__float_as_int(p[o]), 63));
            cur2 = (lane == o) ? (so + b2o) : cur2;
        }

        mem2 = fmaf(bt2, mem2, cur2);
        const float s2 = (mem2 > th2) ? 1.0f : 0.0f;
        mem2 = fmaf(-s2, th2, mem2);

        if (lane < OUT_SZ) {
            const size_t idx = (size_t)t * (B_SZ * OUT_SZ) + (size_t)b * OUT_SZ + lane;
            out_spk[idx] = s2;
            out_mem[idx] = mem2;
        }
    }
}

extern "C" void kernel_launch(void* const* d_in, const int* in_sizes, int n_in,
                              void* d_out, int out_size, void* d_ws, size_t ws_size,
                              hipStream_t stream) {
    const float* x     = (const float*)d_in[0];
    const float* W1    = (const float*)d_in[1];
    const float* b1    = (const float*)d_in[2];
    const float* W2    = (const float*)d_in[3];
    const float* b2    = (const float*)d_in[4];
    const float* beta1 = (const float*)d_in[5];
    const float* thr1  = (const float*)d_in[6];
    const float* beta2 = (const float*)d_in[7];
    const float* thr2  = (const float*)d_in[8];
    float* out = (float*)d_out;

    snn_scan_kernel<<<dim3(B_SZ), dim3(64), 0, stream>>>(
        x, W1, b1, W2, b2, beta1, thr1, beta2, thr2, out);
}